// Round 1
// 634.144 us; speedup vs baseline: 1.0740x; 1.0740x over previous
//
#include <hip/hip_runtime.h>

// StereoDenoiser: disp = clip(depth*128, 0, 128); bilinear horizontal warp of
// img_r by -disp and img_l by +disp (border clamp), average with direct image.
// B=8, C=3, H=1024, W=1920, fp32. Outputs [denoised_l | denoised_r].
//
// V2: full-row LDS staging. Gathers have random ±128-px scatter (depth is
// random), which made per-lane global loads split into ~20 L1 transactions
// each (48 gathers/thread -> L1-bound at 19% of HBM roofline). Stage all
// 6 planes (2 imgs x 3 ch) of the row into LDS coalesced, gather from LDS
// (ds_read2_b32, ~1.5-2x bank-conflict cost only).

constexpr int B = 8, C = 3, H = 1024, W = 1920;
constexpr int HW  = H * W;
constexpr int CHW = C * HW;
constexpr long OUT_HALF = (long)B * CHW;
constexpr float MAX_DISP = 128.0f;
constexpr int W4 = W / 4;            // 480 float4 groups per row
constexpr int LSTRIDE = W + 4;       // 1924: mult-of-4 -> float4-aligned planes,
                                     // slot [1920] is a zero guard (weight-0 tap)

__global__ __launch_bounds__(512) void stereo_denoise(
    const float* __restrict__ img_l, const float* __restrict__ img_r,
    const float* __restrict__ depth, float* __restrict__ out)
{
    __shared__ float lds[6 * LSTRIDE];   // planes 0..2: img_l c; 3..5: img_r c

    const int tid = threadIdx.x;
    const int bh  = blockIdx.x;          // b*H + h
    const int b   = bh >> 10;            // H = 1024
    const long rowD = (long)bh * W;                  // b*HW + h*W (depth row)
    const long rowI = rowD + (long)(2 * b) * HW;     // b*CHW + h*W (image row, c=0)

    // ---- stage: 6 planes x 480 float4, coalesced ----
    for (int i = tid; i < 6 * W4; i += 512) {
        int p  = i / W4;                 // plane 0..5
        int c4 = i - p * W4;             // float4 column
        const float* src = (p < 3 ? img_l : img_r)
                         + rowI + (long)(p < 3 ? p : p - 3) * HW + c4 * 4;
        *reinterpret_cast<float4*>(&lds[p * LSTRIDE + c4 * 4]) =
            *reinterpret_cast<const float4*>(src);
    }
    if (tid < 6) lds[tid * LSTRIDE + W] = 0.0f;   // guard slot: only ever read
                                                  // with weight exactly 0
    __syncthreads();

    if (tid >= W4) return;               // 480 compute threads, 4 px each
    const int w = tid * 4;

    const float4 d4 = *reinterpret_cast<const float4*>(depth + rowD + w);
    const float dv[4] = {d4.x, d4.y, d4.z, d4.w};

    int   i0m[4], i0p[4];
    float wm[4], wp[4];
#pragma unroll
    for (int j = 0; j < 4; ++j) {
        float d  = fminf(fmaxf(dv[j] * MAX_DISP, 0.0f), MAX_DISP);
        float xw = (float)(w + j);
        float xm = fminf(fmaxf(xw - d, 0.0f), (float)(W - 1));  // img_r source
        float xp = fminf(fmaxf(xw + d, 0.0f), (float)(W - 1));  // img_l source
        float fm  = floorf(xm);
        float fp2 = floorf(xp);
        i0m[j] = (int)fm;  wm[j] = xm - fm;
        i0p[j] = (int)fp2; wp[j] = xp - fp2;
        // i0+1 tap read unconditionally: when clamped (x == W-1) the weight is
        // exactly 0 and the tap hits the zeroed guard slot -> contributes 0,
        // matching the reference's min(i0+1, W-1) result bit-exactly.
    }

#pragma unroll
    for (int c = 0; c < C; ++c) {
        const float* pl = &lds[c * LSTRIDE];
        const float* pr = &lds[(3 + c) * LSTRIDE];

        float4 vl = *reinterpret_cast<const float4*>(pl + w);
        float4 vr = *reinterpret_cast<const float4*>(pr + w);
        const float* vlp = &vl.x;
        const float* vrp = &vr.x;

        float4 ol, orr;
        float* olp = &ol.x;
        float* orp = &orr.x;
#pragma unroll
        for (int j = 0; j < 4; ++j) {
            float r0 = pr[i0m[j]], r1 = pr[i0m[j] + 1];   // one ds_read2_b32
            float l0 = pl[i0p[j]], l1 = pl[i0p[j] + 1];   // one ds_read2_b32
            float warped_r = r0 * (1.0f - wm[j]) + r1 * wm[j];
            float warped_l = l0 * (1.0f - wp[j]) + l1 * wp[j];
            olp[j] = (vlp[j] + warped_r) * 0.5f;   // denoised_l
            orp[j] = (vrp[j] + warped_l) * 0.5f;   // denoised_r
        }
        long oidx = rowI + (long)c * HW + w;
        *reinterpret_cast<float4*>(out + oidx)            = ol;
        *reinterpret_cast<float4*>(out + OUT_HALF + oidx) = orr;
    }
}

extern "C" void kernel_launch(void* const* d_in, const int* in_sizes, int n_in,
                              void* d_out, int out_size, void* d_ws, size_t ws_size,
                              hipStream_t stream) {
    const float* img_l = (const float*)d_in[0];
    const float* img_r = (const float*)d_in[1];
    const float* depth = (const float*)d_in[2];
    float* out = (float*)d_out;

    const int grid  = B * H;    // 8192 blocks, one image row each
    const int block = 512;
    stereo_denoise<<<grid, block, 0, stream>>>(img_l, img_r, depth, out);
}